// Round 3
// baseline (60069.879 us; speedup 1.0000x reference)
//
#include <hip/hip_runtime.h>
#include <stdint.h>
#include <stddef.h>

#define T_STEPS 512
#define B_SZ    128
#define DIN     1024
#define H_SZ    2048
#define NG      8192            // 4*H
#define BH      (B_SZ * H_SZ)   // 262144
#define NWG     256

typedef __attribute__((ext_vector_type(8))) short bf16x8;
typedef __attribute__((ext_vector_type(4))) float f32x4;

static __device__ __forceinline__ unsigned short f2bf(float x) {
  unsigned int u = __float_as_uint(x);
  u += 0x7fffu + ((u >> 16) & 1u);   // RNE; inputs finite
  return (unsigned short)(u >> 16);
}

static __device__ __forceinline__ float sigm(float x) {
  return 1.0f / (1.0f + __expf(-x));
}
static __device__ __forceinline__ float tanh_(float x) {
  float e = __expf(-2.0f * fabsf(x));  // in (0,1], no overflow
  float t = (1.0f - e) / (1.0f + e);
  return x < 0.0f ? -t : t;
}

// global -> LDS async copy, 16B per lane. LDS dest is wave-uniform base;
// HW writes lane l at ldst + l*16. Global src IS per-lane (swizzle there).
static __device__ __forceinline__ void async_load16(const void* gsrc, void* ldst) {
  __builtin_amdgcn_global_load_lds(
      (__attribute__((address_space(1))) void*)(const_cast<void*>(gsrc)),
      (__attribute__((address_space(3))) void*)ldst,
      16, 0, 0);
}

// Lean device-scope grid barrier: one atomic per WG, monotone counter.
static __device__ __forceinline__ void grid_barrier(unsigned* cnt, unsigned target) {
  __syncthreads();                       // all WG lanes' stores issued & drained
  if (threadIdx.x == 0) {
    __hip_atomic_fetch_add(cnt, 1u, __ATOMIC_ACQ_REL, __HIP_MEMORY_SCOPE_AGENT);
    while (__hip_atomic_load(cnt, __ATOMIC_ACQUIRE, __HIP_MEMORY_SCOPE_AGENT) < target)
      __builtin_amdgcn_s_sleep(2);
  }
  __syncthreads();                       // publish t0's acquire to whole WG
}

__global__ void cvt_x_bf16(const float4* __restrict__ in, ushort4* __restrict__ out, int n4) {
  int i = blockIdx.x * blockDim.x + threadIdx.x;
  int st = gridDim.x * blockDim.x;
  for (; i < n4; i += st) {
    float4 v = in[i];
    ushort4 o;
    o.x = f2bf(v.x); o.y = f2bf(v.y); o.z = f2bf(v.z); o.w = f2bf(v.w);
    out[i] = o;
  }
}

__global__ void build_wcat(const float* __restrict__ wa, const float* __restrict__ wb,
                           unsigned short* __restrict__ outw, int ka, int K) {
  int k = blockIdx.x * blockDim.x + threadIdx.x;
  int n = blockIdx.y;
  if (k >= K) return;
  int kb = K - ka;
  float v = (k < ka) ? wa[(size_t)n * ka + k]
                     : wb[(size_t)n * kb + (k - ka)];
  outw[(size_t)n * K + k] = f2bf(v);
}

__global__ void init_state(const float* __restrict__ h0, const float* __restrict__ c0,
                           unsigned short* __restrict__ hb0, unsigned short* __restrict__ hb1,
                           float* __restrict__ cws, unsigned* __restrict__ barcnt) {
  int i = blockIdx.x * blockDim.x + threadIdx.x;
  if (i == 0) *barcnt = 0u;              // re-zero barrier counter every call
  if (i < BH) {
    hb0[i] = f2bf(h0[i]);
    hb1[i] = f2bf(h0[BH + i]);
    cws[i] = c0[i];
    cws[BH + i] = c0[BH + i];
  }
}

// One LSTM cell step (device side). gates[128,8192] = A[128,K] @ Wcat^T + b.
// WG owns 8 h-cols (32 gate-cols). Wave wv owns rows [wv*32, wv*32+32).
// 6-deep LDS ring, 5-ahead prefetch, counted vmcnt (5 loads/wave/stage).
// XOR swizzle: chunk' = chunk ^ (row&7), applied at global-src and ds_read.
static __device__ __forceinline__ void lstm_step_body(
    unsigned short (*Abuf)[128 * 64], unsigned short (*Bbuf)[32 * 64],
    const unsigned short* __restrict__ a0, int s0, int ksplit,
    const unsigned short* __restrict__ a1,          // row stride H_SZ
    int K,
    const unsigned short* __restrict__ w,           // [NG][K] bf16
    float bi, float bff, float bg, float bo,
    float* __restrict__ c,                          // [B][H] fp32, in-place (WG-private cols)
    unsigned short* __restrict__ hout,              // [B][H] bf16
    float* __restrict__ fout,                       // optional [B][H] fp32
    int tid, int lane, int wv, int n0)
{
  f32x4 acc[2][2] = {};
  const int KT = K >> 6;

  auto stage = [&](int kt, int bsel) {
    const int kb = kt << 6;
#pragma unroll
    for (int it = 0; it < 4; ++it) {                // A: 128r x 64k = 1024 chunks
      int cid = it * 256 + tid;
      int row = cid >> 3;
      int chs = (cid & 7) ^ (row & 7);
      int kk  = kb + (chs << 3);
      const unsigned short* src =
          (kk < ksplit) ? (a0 + (size_t)row * s0 + kk)
                        : (a1 + (size_t)row * H_SZ + (kk - ksplit));
      async_load16(src, &Abuf[bsel][(it * 256 + wv * 64) * 8]);
    }
    {                                               // B: 32r x 64k = 256 chunks
      int nl  = tid >> 3;
      int chs = (tid & 7) ^ (nl & 7);
      int nn  = ((nl >> 3) << 11) + n0 + (nl & 7);  // gate*2048 + hcol
      const unsigned short* src = w + (size_t)nn * K + kb + (chs << 3);
      async_load16(src, &Bbuf[bsel][(wv * 64) * 8]);
    }
  };

  stage(0, 0); stage(1, 1); stage(2, 2); stage(3, 3); stage(4, 4);
  asm volatile("s_waitcnt vmcnt(20)" ::: "memory");   // stage 0 complete
  __builtin_amdgcn_s_barrier();
  asm volatile("" ::: "memory");

  int cb = 0, sb = 5;
  for (int kt = 0; kt < KT; ++kt) {
    if (kt + 5 < KT) stage(kt + 5, sb);   // overwrites buf read 5 iters (4 barriers) ago

#pragma unroll
    for (int kkk = 0; kkk < 2; ++kkk) {
      const int ch = kkk * 4 + (lane >> 4);          // logical chunk 0..7
      bf16x8 afr[2], bfr[2];
#pragma unroll
      for (int rt = 0; rt < 2; ++rt) {
        int row = wv * 32 + rt * 16 + (lane & 15);
        afr[rt] = *(const bf16x8*)&Abuf[cb][row * 64 + ((ch ^ (row & 7)) << 3)];
      }
#pragma unroll
      for (int ct = 0; ct < 2; ++ct) {
        int nl = ct * 16 + (lane & 15);
        bfr[ct] = *(const bf16x8*)&Bbuf[cb][nl * 64 + ((ch ^ (nl & 7)) << 3)];
      }
#pragma unroll
      for (int rt = 0; rt < 2; ++rt)
#pragma unroll
        for (int ct = 0; ct < 2; ++ct)
          acc[rt][ct] = __builtin_amdgcn_mfma_f32_16x16x32_bf16(afr[rt], bfr[ct], acc[rt][ct], 0, 0, 0);
    }

    if (kt + 1 < KT) {
      int rem = KT - 1 - kt;   // stages outstanding beyond current
      if (rem >= 5)      asm volatile("s_waitcnt vmcnt(20)" ::: "memory");
      else if (rem == 4) asm volatile("s_waitcnt vmcnt(15)" ::: "memory");
      else if (rem == 3) asm volatile("s_waitcnt vmcnt(10)" ::: "memory");
      else if (rem == 2) asm volatile("s_waitcnt vmcnt(5)"  ::: "memory");
      else               asm volatile("s_waitcnt vmcnt(0)"  ::: "memory");
      __builtin_amdgcn_s_barrier();
      asm volatile("" ::: "memory");
    }
    cb = (cb == 5) ? 0 : cb + 1;
    sb = (sb == 5) ? 0 : sb + 1;
  }

  // Epilogue. C/D map: col(nl)=lane&15, row=(lane>>4)*4+r.
  // acc[rt][0] holds gate i (col<8) or f; acc[rt][1] holds g or o.
  const int hc  = n0 + (lane & 7);
  const int hi8 = (lane >> 3) & 1;

#pragma unroll
  for (int r = 0; r < 4; ++r) {
    float vA0 = acc[0][0][r], vA1 = acc[0][1][r];
    float vB0 = acc[1][0][r], vB1 = acc[1][1][r];
    float sA0 = __shfl_xor(vA0, 8), sA1 = __shfl_xor(vA1, 8);
    float sB0 = __shfl_xor(vB0, 8), sB1 = __shfl_xor(vB1, 8);
    float gi, gf, gg, go; int rtm;
    if (!hi8) { gi = vA0; gf = sA0; gg = vA1; go = sA1; rtm = 0; }
    else      { gi = sB0; gf = vB0; gg = sB1; go = vB1; rtm = 1; }
    int row = wv * 32 + rtm * 16 + ((lane >> 4) << 2) + r;
    size_t idx = (size_t)row * H_SZ + hc;
    float iv = sigm(gi + bi);
    float fv = sigm(gf + bff);
    float gv = tanh_(gg + bg);
    float ov = sigm(go + bo);
    float cn = fv * c[idx] + iv * gv;
    c[idx] = cn;
    float hn = ov * tanh_(cn);
    hout[idx] = f2bf(hn);
    if (fout) fout[idx] = hn;
  }
}

__global__ __launch_bounds__(256) void lstm_persistent(
    const unsigned short* __restrict__ xbf,
    const unsigned short* __restrict__ Wc0,
    const unsigned short* __restrict__ Wc1,
    unsigned short* __restrict__ hb0,
    unsigned short* __restrict__ hb1,
    float* __restrict__ cws,
    const float* __restrict__ b0,
    const float* __restrict__ b1,
    float* __restrict__ out,
    unsigned* __restrict__ barcnt)
{
  __shared__ __align__(16) unsigned short Abuf[6][128 * 64];  // 96 KB
  __shared__ __align__(16) unsigned short Bbuf[6][32 * 64];   // 24 KB

  const int tid  = threadIdx.x;
  const int lane = tid & 63;
  const int wv   = tid >> 6;
  const int n0   = blockIdx.x << 3;
  const int hc   = n0 + (lane & 7);

  // biases are fixed per WG: hoist to registers once
  const float b0i = b0[hc], b0f = b0[H_SZ + hc], b0g = b0[2 * H_SZ + hc], b0o = b0[3 * H_SZ + hc];
  const float b1i = b1[hc], b1f = b1[H_SZ + hc], b1g = b1[2 * H_SZ + hc], b1o = b1[3 * H_SZ + hc];

  unsigned phase = 0;
  for (int t = 0; t < T_STEPS; ++t) {
    const int p = t & 1;
    lstm_step_body(Abuf, Bbuf,
                   xbf + (size_t)t * B_SZ * DIN, DIN, DIN,
                   hb0 + (size_t)p * BH, 3072, Wc0,
                   b0i, b0f, b0g, b0o,
                   cws, hb0 + (size_t)(p ^ 1) * BH, nullptr,
                   tid, lane, wv, n0);
    ++phase; grid_barrier(barcnt, phase * NWG);
    lstm_step_body(Abuf, Bbuf,
                   hb0 + (size_t)(p ^ 1) * BH, H_SZ, H_SZ,
                   hb1 + (size_t)p * BH, 4096, Wc1,
                   b1i, b1f, b1g, b1o,
                   cws + BH, hb1 + (size_t)(p ^ 1) * BH,
                   (t == T_STEPS - 1) ? out : nullptr,
                   tid, lane, wv, n0);
    ++phase; grid_barrier(barcnt, phase * NWG);
  }
}

extern "C" void kernel_launch(void* const* d_in, const int* in_sizes, int n_in,
                              void* d_out, int out_size, void* d_ws, size_t ws_size,
                              hipStream_t stream) {
  (void)in_sizes; (void)n_in; (void)out_size; (void)ws_size;
  const float* x    = (const float*)d_in[0];
  const float* h0   = (const float*)d_in[1];
  const float* c0   = (const float*)d_in[2];
  const float* Wih0 = (const float*)d_in[3];
  const float* Whh0 = (const float*)d_in[4];
  const float* b0   = (const float*)d_in[5];
  const float* Wih1 = (const float*)d_in[6];
  const float* Whh1 = (const float*)d_in[7];
  const float* b1   = (const float*)d_in[8];
  float* out = (float*)d_out;

  unsigned short* xbf = (unsigned short*)d_ws;                     // 512*128*1024 bf16
  unsigned short* Wc0 = xbf + (size_t)T_STEPS * B_SZ * DIN;        // 8192*3072
  unsigned short* Wc1 = Wc0 + (size_t)NG * 3072;                   // 8192*4096
  unsigned short* hb0 = Wc1 + (size_t)NG * 4096;                   // 2 * BH
  unsigned short* hb1 = hb0 + 2 * (size_t)BH;                      // 2 * BH
  float*          cws = (float*)(hb1 + 2 * (size_t)BH);            // 2 * BH fp32
  unsigned*       bar = (unsigned*)(cws + 2 * (size_t)BH);         // 1 u32

  cvt_x_bf16<<<dim3(4096), dim3(256), 0, stream>>>(
      (const float4*)x, (ushort4*)xbf, T_STEPS * B_SZ * DIN / 4);
  build_wcat<<<dim3(12, NG), dim3(256), 0, stream>>>(Wih0, Whh0, Wc0, DIN, 3072);
  build_wcat<<<dim3(16, NG), dim3(256), 0, stream>>>(Wih1, Whh1, Wc1, H_SZ, 4096);
  init_state<<<dim3(BH / 256), dim3(256), 0, stream>>>(h0, c0, hb0, hb1, cws, bar);

  const unsigned short* xbf_c = xbf;
  const unsigned short* Wc0_c = Wc0;
  const unsigned short* Wc1_c = Wc1;
  unsigned short* hb0_c = hb0;
  unsigned short* hb1_c = hb1;
  float* cws_c = cws;
  const float* b0_c = b0;
  const float* b1_c = b1;
  float* out_c = out;
  unsigned* bar_c = bar;
  void* args[] = { &xbf_c, &Wc0_c, &Wc1_c, &hb0_c, &hb1_c, &cws_c,
                   &b0_c, &b1_c, &out_c, &bar_c };
  hipLaunchCooperativeKernel((void*)lstm_persistent, dim3(NWG), dim3(256),
                             args, 0, stream);
}

// Round 6
// 32409.055 us; speedup vs baseline: 1.8535x; 1.8535x over previous
//
#include <hip/hip_runtime.h>
#include <stdint.h>
#include <stddef.h>

#define T_STEPS 512
#define B_SZ    128
#define DIN     1024
#define H_SZ    2048
#define NG      8192            // 4*H
#define BH      (B_SZ * H_SZ)   // 262144

typedef __attribute__((ext_vector_type(8))) short bf16x8;
typedef __attribute__((ext_vector_type(4))) float f32x4;

static __device__ __forceinline__ unsigned short f2bf(float x) {
  unsigned int u = __float_as_uint(x);
  u += 0x7fffu + ((u >> 16) & 1u);   // RNE; inputs finite
  return (unsigned short)(u >> 16);
}

static __device__ __forceinline__ float sigm(float x) {
  return 1.0f / (1.0f + __expf(-x));
}
static __device__ __forceinline__ float tanh_(float x) {
  float e = __expf(-2.0f * fabsf(x));  // in (0,1], no overflow
  float t = (1.0f - e) / (1.0f + e);
  return x < 0.0f ? -t : t;
}

// global -> LDS async copy, 16B per lane. LDS dest is wave-uniform base;
// HW writes lane l at ldst + l*16. Global src IS per-lane (swizzle there).
static __device__ __forceinline__ void async_load16(const void* gsrc, void* ldst) {
  __builtin_amdgcn_global_load_lds(
      (__attribute__((address_space(1))) void*)(const_cast<void*>(gsrc)),
      (__attribute__((address_space(3))) void*)ldst,
      16, 0, 0);
}

// Barrier that memory ops cannot be compiler-moved across (rd4's NaN fix).
static __device__ __forceinline__ void wg_barrier_pinned() {
  __builtin_amdgcn_s_barrier();
  asm volatile("" ::: "memory");
  __builtin_amdgcn_sched_barrier(0);
}

__global__ void cvt_x_bf16(const float4* __restrict__ in, ushort4* __restrict__ out, int n4) {
  int i = blockIdx.x * blockDim.x + threadIdx.x;
  int st = gridDim.x * blockDim.x;
  for (; i < n4; i += st) {
    float4 v = in[i];
    ushort4 o;
    o.x = f2bf(v.x); o.y = f2bf(v.y); o.z = f2bf(v.z); o.w = f2bf(v.w);
    out[i] = o;
  }
}

__global__ void build_wcat(const float* __restrict__ wa, const float* __restrict__ wb,
                           unsigned short* __restrict__ outw, int ka, int K) {
  int k = blockIdx.x * blockDim.x + threadIdx.x;
  int n = blockIdx.y;
  if (k >= K) return;
  int kb = K - ka;
  float v = (k < ka) ? wa[(size_t)n * ka + k]
                     : wb[(size_t)n * kb + (k - ka)];
  outw[(size_t)n * K + k] = f2bf(v);
}

__global__ void init_state(const float* __restrict__ h0, const float* __restrict__ c0,
                           unsigned short* __restrict__ hb0, unsigned short* __restrict__ hb1,
                           float* __restrict__ cws) {
  int i = blockIdx.x * blockDim.x + threadIdx.x;
  if (i < BH) {
    hb0[i] = f2bf(h0[i]);
    hb1[i] = f2bf(h0[BH + i]);
    cws[i] = c0[i];
    cws[BH + i] = c0[BH + i];
  }
}

// One LSTM cell step. gates[128,8192] = A[128,K] @ Wcat^T + b; A = concat(a0|a1).
// WG owns 8 h-cols (32 gate-cols). Wave wv owns rows [wv*32, wv*32+32).
// A-fragments: direct global->register, 4 named sets (unroll-4), 4-ahead.
// B (weights): LDS ring of 8 x 4KB, staged 7 ahead via global_load_lds, XOR-swizzled.
// vmcnt retires IN ORDER, so "B(kt+1) retired" <=> "outstanding <= #ops issued
// after it". At full depth that count is 34 (6 stageB + 28 loadA); tail shrinks.
template<int K, int KSPLIT>
static __device__ __forceinline__ void lstm_step_body(
    unsigned short (*Bbuf)[32 * 64],
    const unsigned short* __restrict__ a0,   // [128][KSPLIT] row-major
    const unsigned short* __restrict__ a1,   // [128][H_SZ] row-major
    const unsigned short* __restrict__ w,    // [NG][K] bf16
    const float* __restrict__ bias,          // [NG] fp32
    float* __restrict__ c,                   // [B][H] fp32, in-place (WG-private cols)
    unsigned short* __restrict__ hout,       // [B][H] bf16
    float* __restrict__ fout,                // optional [B][H] fp32
    int tid, int lane, int wv, int n0)
{
  constexpr int KT = K >> 6;   // 48 or 64, divisible by 4
  f32x4 acc[2][2] = {};

  const unsigned short* r0p[2];
  const unsigned short* r1p[2];
#pragma unroll
  for (int rt = 0; rt < 2; ++rt) {
    int row = wv * 32 + rt * 16 + (lane & 15);
    r0p[rt] = a0 + (size_t)row * KSPLIT;
    r1p[rt] = a1 + (size_t)row * H_SZ;
  }
  const int klo = (lane >> 4) << 3;   // lane-group k offset (elems)

  auto loadA = [&](int kt, bf16x8 (&A)[2][2]) {
    const int kb = kt << 6;
    const bool sA = kb < KSPLIT;     // tiles never straddle (KSPLIT % 64 == 0)
    const int off = (sA ? kb : kb - KSPLIT) + klo;
#pragma unroll
    for (int rt = 0; rt < 2; ++rt) {
      const unsigned short* bp = (sA ? r0p[rt] : r1p[rt]) + off;
      A[rt][0] = *(const bf16x8*)(bp);
      A[rt][1] = *(const bf16x8*)(bp + 32);
    }
  };

  auto stageB = [&](int kt) {
    const int kb = kt << 6;
    int nl  = tid >> 3;                              // 32 gate-rows
    int chs = (tid & 7) ^ (nl & 7);                  // pre-swizzled source chunk
    int nn  = ((nl >> 3) << 11) + n0 + (nl & 7);     // gate*2048 + hcol
    const unsigned short* src = w + (size_t)nn * K + kb + (chs << 3);
    async_load16(src, &Bbuf[kt & 7][(wv * 64) * 8]);
  };

  auto iter = [&](int kt, bf16x8 (&A)[2][2]) {
    if (kt + 7 < KT) stageB(kt + 7);                 // issue stage early
    const int bq = kt & 7;
#pragma unroll
    for (int kkk = 0; kkk < 2; ++kkk) {
      bf16x8 bfr[2];
#pragma unroll
      for (int ct = 0; ct < 2; ++ct) {
        int nl = ct * 16 + (lane & 15);
        int ch = kkk * 4 + (lane >> 4);
        bfr[ct] = *(const bf16x8*)&Bbuf[bq][nl * 64 + ((ch ^ (nl & 7)) << 3)];
      }
#pragma unroll
      for (int rt = 0; rt < 2; ++rt)
#pragma unroll
        for (int ct = 0; ct < 2; ++ct)
          acc[rt][ct] = __builtin_amdgcn_mfma_f32_16x16x32_bf16(A[rt][kkk], bfr[ct], acc[rt][ct], 0, 0, 0);
    }
    if (kt + 4 < KT) loadA(kt + 4, A);               // refill own named set post-use
    // Exact ladder: ops issued after stageB(kt+1) =
    //   min(6, rem-1) later stageB + 4 * #loadA(kt-2 .. min(kt+4, KT-1)).
    int rem = KT - 1 - kt;
    if (rem >= 7)      asm volatile("s_waitcnt vmcnt(34)" ::: "memory");
    else if (rem == 6) asm volatile("s_waitcnt vmcnt(33)" ::: "memory");
    else if (rem == 5) asm volatile("s_waitcnt vmcnt(32)" ::: "memory");
    else if (rem == 4) asm volatile("s_waitcnt vmcnt(31)" ::: "memory");
    else if (rem == 3) asm volatile("s_waitcnt vmcnt(26)" ::: "memory");
    else if (rem == 2) asm volatile("s_waitcnt vmcnt(21)" ::: "memory");
    else if (rem == 1) asm volatile("s_waitcnt vmcnt(16)" ::: "memory");
    wg_barrier_pinned();   // rem==0: plain pinned barrier (reads already consumed)
  };

  bf16x8 A0[2][2], A1[2][2], A2[2][2], A3[2][2];
  // Prologue queue: B0,A0x4,B1,A1x4,B2,A2x4,B3,A3x4,B4,B5,B6 = 23 ops; retire B0.
  stageB(0); loadA(0, A0);
  stageB(1); loadA(1, A1);
  stageB(2); loadA(2, A2);
  stageB(3); loadA(3, A3);
  stageB(4); stageB(5); stageB(6);
  asm volatile("s_waitcnt vmcnt(22)" ::: "memory");
  wg_barrier_pinned();

  for (int kt = 0; kt < KT; kt += 4) {
    iter(kt,     A0);
    iter(kt + 1, A1);
    iter(kt + 2, A2);
    iter(kt + 3, A3);
  }

  // Epilogue. C/D map: col(nl)=lane&15, row=(lane>>4)*4+r.
  // acc[rt][0] = gate i (col<8) or f; acc[rt][1] = g or o.
  const int hc  = n0 + (lane & 7);
  const float bi  = bias[hc];
  const float bff = bias[H_SZ + hc];
  const float bg  = bias[2 * H_SZ + hc];
  const float bo  = bias[3 * H_SZ + hc];
  const int hi8 = (lane >> 3) & 1;

#pragma unroll
  for (int r = 0; r < 4; ++r) {
    float vA0 = acc[0][0][r], vA1 = acc[0][1][r];
    float vB0 = acc[1][0][r], vB1 = acc[1][1][r];
    float sA0 = __shfl_xor(vA0, 8), sA1 = __shfl_xor(vA1, 8);
    float sB0 = __shfl_xor(vB0, 8), sB1 = __shfl_xor(vB1, 8);
    float gi, gf, gg, go; int rtm;
    if (!hi8) { gi = vA0; gf = sA0; gg = vA1; go = sA1; rtm = 0; }
    else      { gi = sB0; gf = vB0; gg = sB1; go = vB1; rtm = 1; }
    int row = wv * 32 + rtm * 16 + ((lane >> 4) << 2) + r;
    size_t idx = (size_t)row * H_SZ + hc;
    float iv = sigm(gi + bi);
    float fv = sigm(gf + bff);
    float gv = tanh_(gg + bg);
    float ov = sigm(go + bo);
    float cn = fv * c[idx] + iv * gv;
    c[idx] = cn;
    float hn = ov * tanh_(cn);
    hout[idx] = f2bf(hn);
    if (fout) fout[idx] = hn;
  }
}

// Single step (edges of the schedule).
template<int K, int KSPLIT>
__global__ __launch_bounds__(256) void lstm_one(
    const unsigned short* __restrict__ a0, const unsigned short* __restrict__ a1,
    const unsigned short* __restrict__ w,  const float* __restrict__ bias,
    float* __restrict__ c, unsigned short* __restrict__ hout, float* __restrict__ fout)
{
  __shared__ __align__(16) unsigned short Bbuf[8][32 * 64];   // 32 KB
  const int tid = threadIdx.x, lane = tid & 63, wv = tid >> 6, n0 = blockIdx.x << 3;
  lstm_step_body<K, KSPLIT>(Bbuf, a0, a1, w, bias, c, hout, fout, tid, lane, wv, n0);
}

// Fused pair: L1(t) then L0(t+1). The two bodies are independent (both read only
// buffers published at the preceding dispatch boundary; writes are read by no
// body in this dispatch) -> no internal grid sync needed; pipelines overlap at
// the seam.
template<int K1, int KS1, int K2, int KS2>
__global__ __launch_bounds__(256) void lstm_pair(
    const unsigned short* __restrict__ a0_1, const unsigned short* __restrict__ a1_1,
    const unsigned short* __restrict__ w1,   const float* __restrict__ bias1,
    float* __restrict__ c1, unsigned short* __restrict__ h1out,
    const unsigned short* __restrict__ a0_2, const unsigned short* __restrict__ a1_2,
    const unsigned short* __restrict__ w2,   const float* __restrict__ bias2,
    float* __restrict__ c2, unsigned short* __restrict__ h2out)
{
  __shared__ __align__(16) unsigned short Bbuf[8][32 * 64];   // 32 KB
  const int tid = threadIdx.x, lane = tid & 63, wv = tid >> 6, n0 = blockIdx.x << 3;
  lstm_step_body<K1, KS1>(Bbuf, a0_1, a1_1, w1, bias1, c1, h1out, nullptr, tid, lane, wv, n0);
  lstm_step_body<K2, KS2>(Bbuf, a0_2, a1_2, w2, bias2, c2, h2out, nullptr, tid, lane, wv, n0);
}

extern "C" void kernel_launch(void* const* d_in, const int* in_sizes, int n_in,
                              void* d_out, int out_size, void* d_ws, size_t ws_size,
                              hipStream_t stream) {
  (void)in_sizes; (void)n_in; (void)out_size; (void)ws_size;
  const float* x    = (const float*)d_in[0];
  const float* h0   = (const float*)d_in[1];
  const float* c0   = (const float*)d_in[2];
  const float* Wih0 = (const float*)d_in[3];
  const float* Whh0 = (const float*)d_in[4];
  const float* b0   = (const float*)d_in[5];
  const float* Wih1 = (const float*)d_in[6];
  const float* Whh1 = (const float*)d_in[7];
  const float* b1   = (const float*)d_in[8];
  float* out = (float*)d_out;

  unsigned short* xbf = (unsigned short*)d_ws;                     // 512*128*1024 bf16
  unsigned short* Wc0 = xbf + (size_t)T_STEPS * B_SZ * DIN;        // 8192*3072
  unsigned short* Wc1 = Wc0 + (size_t)NG * 3072;                   // 8192*4096
  unsigned short* hb0 = Wc1 + (size_t)NG * 4096;                   // 2 * BH (ping-pong)
  unsigned short* hb1 = hb0 + 2 * (size_t)BH;                      // 2 * BH
  float*          cws = (float*)(hb1 + 2 * (size_t)BH);            // 2 * BH fp32

  cvt_x_bf16<<<dim3(4096), dim3(256), 0, stream>>>(
      (const float4*)x, (ushort4*)xbf, T_STEPS * B_SZ * DIN / 4);
  build_wcat<<<dim3(12, NG), dim3(256), 0, stream>>>(Wih0, Whh0, Wc0, DIN, 3072);
  build_wcat<<<dim3(16, NG), dim3(256), 0, stream>>>(Wih1, Whh1, Wc1, H_SZ, 4096);
  init_state<<<dim3(BH / 256), dim3(256), 0, stream>>>(h0, c0, hb0, hb1, cws);

  // Schedule: L0(0); { L1(t) + L0(t+1) } t=0..510; L1(511)->out.
  // h slots: L0(t) reads hb0[t&1], writes hb0[(t+1)&1];
  //          L1(t) reads hb0[(t+1)&1], hb1[t&1], writes hb1[(t+1)&1].
  lstm_one<3072, 1024><<<dim3(256), dim3(256), 0, stream>>>(
      xbf, hb0 + 0, Wc0, b0, cws, hb0 + BH, nullptr);

  for (int t = 0; t < T_STEPS - 1; ++t) {
    const unsigned short* h0cur = hb0 + (size_t)((t + 1) & 1) * BH;
    lstm_pair<4096, 2048, 3072, 1024><<<dim3(256), dim3(256), 0, stream>>>(
        /*L1(t)*/   h0cur, hb1 + (size_t)(t & 1) * BH, Wc1, b1,
                    cws + BH, hb1 + (size_t)((t + 1) & 1) * BH,
        /*L0(t+1)*/ xbf + (size_t)(t + 1) * B_SZ * DIN, h0cur, Wc0, b0,
                    cws, hb0 + (size_t)(t & 1) * BH);
  }
  // L1(511): reads hb0[0], hb1[1]; writes hb1[0] and fp32 out.
  lstm_one<4096, 2048><<<dim3(256), dim3(256), 0, stream>>>(
      hb0 + 0, hb1 + BH, Wc1, b1, cws + BH, hb1 + 0, out);
}